// Round 1
// baseline (342.491 us; speedup 1.0000x reference)
//
#include <hip/hip_runtime.h>

// GCN layer: out = relu(segment_sum(feature[edge_src] by edge_dst) @ W + b)
// N=50000 nodes, E=800000 edges, D=128. All fp32.
//
// Strategy: bucketed CSR (CAP=64 slots/node, Poisson(16) degrees, max~45) built
// with int atomics, then one fused kernel per 16-node tile:
//   phase 1: per-wave gather-sum of source rows (coalesced 512B loads) -> LDS
//   phase 2: register-blocked fp32 GEMM epilogue with W staged in LDS.

constexpr int N   = 50000;
constexpr int E   = 800000;
constexpr int D   = 128;
constexpr int CAP = 64;    // bucket capacity per node
constexpr int NPB = 16;    // nodes per block
constexpr int HS  = 132;   // h_s row stride (pad 128->132 breaks bank aliasing)

__global__ void init_cnt(int* __restrict__ cnt) {
    int i = blockIdx.x * blockDim.x + threadIdx.x;
    if (i < N) cnt[i] = 0;
}

__global__ void scatter_edges(const int* __restrict__ esrc,
                              const int* __restrict__ edst,
                              int* __restrict__ cnt,
                              int* __restrict__ bucket) {
    int e = blockIdx.x * blockDim.x + threadIdx.x;
    if (e >= E) return;
    int d   = edst[e];
    int pos = atomicAdd(&cnt[d], 1);
    if (pos < CAP) bucket[d * CAP + pos] = esrc[e];
}

__global__ __launch_bounds__(256, 2) void gcn_fused(
        const float* __restrict__ feature,
        const int*   __restrict__ cnt,
        const int*   __restrict__ bucket,
        const float* __restrict__ W,
        const float* __restrict__ bias,
        float*       __restrict__ out) {
    __shared__ float W_s[D * D];       // 64 KB
    __shared__ float h_s[NPB * HS];    // 8.25 KB
    __shared__ float b_s[D];

    const int tid      = threadIdx.x;   // 0..255
    const int wave     = tid >> 6;      // 0..3
    const int lane     = tid & 63;
    const int nodeBase = blockIdx.x * NPB;

    // ---- stage W (64KB) and b into LDS, cooperatively, float4 ----
    const float4* W4  = (const float4*)W;
    float4*       Ws4 = (float4*)W_s;
    #pragma unroll
    for (int i = 0; i < (D * D / 4) / 256; ++i)   // 16 iters
        Ws4[tid + i * 256] = W4[tid + i * 256];
    if (tid < D) b_s[tid] = bias[tid];

    // ---- phase 1: each wave gather-sums 4 nodes (independent chains) ----
    const int n0 = nodeBase + wave * 4;
    int deg[4], srcs[4];
    #pragma unroll
    for (int j = 0; j < 4; ++j) {
        int node = n0 + j;
        int dg   = cnt[node];
        dg       = dg > CAP ? CAP : dg;
        deg[j]   = dg;
        srcs[j]  = (lane < dg) ? bucket[node * CAP + lane] : 0;
    }
    float2 acc[4];
    #pragma unroll
    for (int j = 0; j < 4; ++j) acc[j] = make_float2(0.f, 0.f);

    const int maxdeg = max(max(deg[0], deg[1]), max(deg[2], deg[3]));
    for (int i = 0; i < maxdeg; ++i) {
        #pragma unroll
        for (int j = 0; j < 4; ++j) {
            if (i < deg[j]) {                       // wave-uniform branch
                int s = __shfl(srcs[j], i);
                const float2 f =
                    *(const float2*)(feature + s * D + lane * 2);
                acc[j].x += f.x;
                acc[j].y += f.y;
            }
        }
    }
    #pragma unroll
    for (int j = 0; j < 4; ++j)
        *(float2*)(h_s + (wave * 4 + j) * HS + lane * 2) = acc[j];

    __syncthreads();

    // ---- phase 2: out[16 x 128] = relu(h_s @ W_s + b) ----
    // thread t: node = t>>4 (0..15), cols = (t&15)*8 .. +7
    const int node = tid >> 4;
    const int colg = tid & 15;
    float a[8];
    #pragma unroll
    for (int j = 0; j < 8; ++j) a[j] = b_s[colg * 8 + j];

    const float* hp = h_s + node * HS;
    const float* wp = W_s + colg * 8;
    #pragma unroll 4
    for (int k = 0; k < D; ++k) {
        const float  hv = hp[k];                        // 16-lane broadcast
        const float4 w0 = *(const float4*)(wp + k * D);
        const float4 w1 = *(const float4*)(wp + k * D + 4);
        a[0] += hv * w0.x; a[1] += hv * w0.y;
        a[2] += hv * w0.z; a[3] += hv * w0.w;
        a[4] += hv * w1.x; a[5] += hv * w1.y;
        a[6] += hv * w1.z; a[7] += hv * w1.w;
    }

    float4 o0, o1;
    o0.x = fmaxf(a[0], 0.f); o0.y = fmaxf(a[1], 0.f);
    o0.z = fmaxf(a[2], 0.f); o0.w = fmaxf(a[3], 0.f);
    o1.x = fmaxf(a[4], 0.f); o1.y = fmaxf(a[5], 0.f);
    o1.z = fmaxf(a[6], 0.f); o1.w = fmaxf(a[7], 0.f);

    float* op = out + (size_t)(nodeBase + node) * D + colg * 8;
    *(float4*)op       = o0;
    *(float4*)(op + 4) = o1;
}

extern "C" void kernel_launch(void* const* d_in, const int* in_sizes, int n_in,
                              void* d_out, int out_size, void* d_ws, size_t ws_size,
                              hipStream_t stream) {
    const float* feature = (const float*)d_in[0];
    const int*   esrc    = (const int*)d_in[1];
    const int*   edst    = (const int*)d_in[2];
    const float* W       = (const float*)d_in[3];
    const float* bias    = (const float*)d_in[4];
    float*       out     = (float*)d_out;

    // workspace layout: cnt[N] ints, then bucket[N*CAP] ints (~13 MB total)
    int* cnt    = (int*)d_ws;
    int* bucket = cnt + N;

    init_cnt<<<(N + 255) / 256, 256, 0, stream>>>(cnt);
    scatter_edges<<<(E + 255) / 256, 256, 0, stream>>>(esrc, edst, cnt, bucket);
    gcn_fused<<<N / NPB, 256, 0, stream>>>(feature, cnt, bucket, W, bias, out);
}

// Round 2
// 213.694 us; speedup vs baseline: 1.6027x; 1.6027x over previous
//
#include <hip/hip_runtime.h>
#include <hip/hip_fp16.h>

// GCN layer: out = relu(segment_sum(feature[edge_src] by edge_dst) @ W + b)
// Key algebraic move: transform-then-aggregate (linear ops commute):
//   out = relu(segment_sum(Z[src]) + b), Z = feature @ W   (D_out == D_in)
// Z stored fp16 -> gather traffic halves (205 MB vs 410 MB at L2 level).
//
// Pipeline: init_cnt -> scatter_edges (bucketed CSR, ushort ids) ->
//           transform (fp32 vector GEMM, Z fp16) -> gather (wave/node).

constexpr int N   = 50000;
constexpr int E   = 800000;
constexpr int D   = 128;
constexpr int CAP = 64;    // bucket slots/node; Poisson(16) max deg ~45
constexpr int TN  = 16;    // nodes per transform block
constexpr int FS  = 132;   // f_s padded stride (breaks 4-way bank alias)

typedef __attribute__((ext_vector_type(8))) _Float16 half8;

__global__ void init_cnt(int* __restrict__ cnt) {
    int i = blockIdx.x * blockDim.x + threadIdx.x;
    if (i < N) cnt[i] = 0;
}

__global__ void scatter_edges(const int* __restrict__ esrc,
                              const int* __restrict__ edst,
                              int* __restrict__ cnt,
                              unsigned short* __restrict__ bucket) {
    int e = blockIdx.x * blockDim.x + threadIdx.x;
    if (e >= E) return;
    int d   = edst[e];
    int pos = atomicAdd(&cnt[d], 1);
    if (pos < CAP) bucket[d * CAP + pos] = (unsigned short)esrc[e];
}

// Z = feature @ W, store fp16. block 256 = 16 nodes x 16 col-groups.
__global__ __launch_bounds__(256, 2) void transform(
        const float* __restrict__ feature,
        const float* __restrict__ W,
        _Float16*    __restrict__ Z) {
    __shared__ float W_s[D * D];     // 64 KB
    __shared__ float f_s[TN * FS];   // 8.25 KB

    const int tid = threadIdx.x;
    const int nodeBase = blockIdx.x * TN;

    const float4* W4  = (const float4*)W;
    float4*       Ws4 = (float4*)W_s;
    #pragma unroll
    for (int i = 0; i < (D * D / 4) / 256; ++i)   // 16 iters
        Ws4[tid + i * 256] = W4[tid + i * 256];

    const int n  = tid >> 4;          // 0..15 node-in-block
    const int c16 = tid & 15;         // col-group / k-chunk
    const int k0 = c16 * 8;
    const float4* fr = (const float4*)(feature + (size_t)(nodeBase + n) * D + k0);
    *(float4*)(f_s + n * FS + k0)     = fr[0];
    *(float4*)(f_s + n * FS + k0 + 4) = fr[1];
    __syncthreads();

    float a[8] = {0.f, 0.f, 0.f, 0.f, 0.f, 0.f, 0.f, 0.f};
    const float* hp = f_s + n * FS;
    const float* wp = W_s + c16 * 8;
    #pragma unroll 4
    for (int k = 0; k < D; ++k) {
        const float  hv = hp[k];                     // broadcast among 16 lanes
        const float4 w0 = *(const float4*)(wp + k * D);
        const float4 w1 = *(const float4*)(wp + k * D + 4);
        a[0] += hv * w0.x; a[1] += hv * w0.y;
        a[2] += hv * w0.z; a[3] += hv * w0.w;
        a[4] += hv * w1.x; a[5] += hv * w1.y;
        a[6] += hv * w1.z; a[7] += hv * w1.w;
    }

    half8 z;
    #pragma unroll
    for (int j = 0; j < 8; ++j) z[j] = (_Float16)a[j];
    *(half8*)(Z + (size_t)(nodeBase + n) * D + c16 * 8) = z;
}

// out[node] = relu(sum_{s in bucket[node]} Z[s] + b)
// One wave per node: 64 lanes = 4 row-groups x 16 col-lanes (16B each).
__global__ __launch_bounds__(256, 4) void gather(
        const _Float16*      __restrict__ Z,
        const int*           __restrict__ cnt,
        const unsigned short* __restrict__ bucket,
        const float*         __restrict__ bias,
        float*               __restrict__ out) {
    const int tid  = threadIdx.x;
    const int wave = tid >> 6;
    const int lane = tid & 63;
    const int node = blockIdx.x * 4 + wave;
    const int g    = lane >> 4;    // row-group 0..3
    const int li   = lane & 15;    // col-lane: cols li*8..+7

    int deg = cnt[node];
    deg = deg > CAP ? CAP : deg;
    const int src = bucket[node * CAP + lane];   // slot = lane (CAP==64)

    float a0[8] = {0,0,0,0,0,0,0,0};
    float a1[8] = {0,0,0,0,0,0,0,0};

    for (int base = 0; base < deg; base += 8) {
        const int r0 = base + g;
        const int r1 = base + 4 + g;
        const int i0 = min(r0, deg - 1);
        const int i1 = min(r1, deg - 1);
        const int s0 = __shfl(src, i0);
        const int s1 = __shfl(src, i1);
        const float m0 = (r0 < deg) ? 1.f : 0.f;
        const float m1 = (r1 < deg) ? 1.f : 0.f;
        const half8 h0 = *(const half8*)(Z + (size_t)s0 * D + li * 8);
        const half8 h1 = *(const half8*)(Z + (size_t)s1 * D + li * 8);
        #pragma unroll
        for (int j = 0; j < 8; ++j) {
            a0[j] += m0 * (float)h0[j];
            a1[j] += m1 * (float)h1[j];
        }
    }

    #pragma unroll
    for (int j = 0; j < 8; ++j) {
        a0[j] += a1[j];
        a0[j] += __shfl_xor(a0[j], 16);   // combine row-groups
        a0[j] += __shfl_xor(a0[j], 32);
    }

    if (g == 0) {
        const float4 b0 = *(const float4*)(bias + li * 8);
        const float4 b1 = *(const float4*)(bias + li * 8 + 4);
        float4 o0, o1;
        o0.x = fmaxf(a0[0] + b0.x, 0.f); o0.y = fmaxf(a0[1] + b0.y, 0.f);
        o0.z = fmaxf(a0[2] + b0.z, 0.f); o0.w = fmaxf(a0[3] + b0.w, 0.f);
        o1.x = fmaxf(a0[4] + b1.x, 0.f); o1.y = fmaxf(a0[5] + b1.y, 0.f);
        o1.z = fmaxf(a0[6] + b1.z, 0.f); o1.w = fmaxf(a0[7] + b1.w, 0.f);
        float* op = out + (size_t)node * D + li * 8;
        *(float4*)op       = o0;
        *(float4*)(op + 4) = o1;
    }
}

extern "C" void kernel_launch(void* const* d_in, const int* in_sizes, int n_in,
                              void* d_out, int out_size, void* d_ws, size_t ws_size,
                              hipStream_t stream) {
    const float* feature = (const float*)d_in[0];
    const int*   esrc    = (const int*)d_in[1];
    const int*   edst    = (const int*)d_in[2];
    const float* W       = (const float*)d_in[3];
    const float* bias    = (const float*)d_in[4];
    float*       out     = (float*)d_out;

    // ws layout: cnt int[N] (200 KB) | bucket ushort[N*CAP] (6.4 MB) |
    //            Z fp16[N*D] (12.8 MB)  -> 19.4 MB total
    int*            cnt    = (int*)d_ws;
    unsigned short* bucket = (unsigned short*)(cnt + N);
    _Float16*       Z      = (_Float16*)(bucket + (size_t)N * CAP);

    init_cnt<<<(N + 255) / 256, 256, 0, stream>>>(cnt);
    scatter_edges<<<(E + 255) / 256, 256, 0, stream>>>(esrc, edst, cnt, bucket);
    transform<<<N / TN, 256, 0, stream>>>(feature, W, Z);
    gather<<<N / 4, 256, 0, stream>>>(Z, cnt, bucket, bias, out);
}

// Round 3
// 157.369 us; speedup vs baseline: 2.1764x; 1.3579x over previous
//
#include <hip/hip_runtime.h>
#include <hip/hip_fp16.h>

// GCN layer: out = relu(segment_sum(feature[edge_src] by edge_dst) @ W + b)
// Transform-then-aggregate: Z = feature @ W (MFMA f16, fp32 acc), then
// out = relu(segsum(Z[src]) + b).
//
// Pipeline: memset(cnt) -> prep_w (W -> f16 fragment layout) ->
//   prep [fused: even blocks scatter edges into bucketed CSR,
//         odd blocks MFMA-transform 64 nodes] -> gather (wave/node).

constexpr int N   = 50000;
constexpr int E   = 800000;
constexpr int D   = 128;
constexpr int CAP = 64;     // bucket slots/node; Poisson(16) max deg ~45
constexpr int NT  = 3125;   // 16-node tiles
constexpr int ZSTR = 136;   // LDS f16 row stride (pad 128->136: conflict-free)

using f16x8 = __attribute__((ext_vector_type(8))) _Float16;
using f32x4 = __attribute__((ext_vector_type(4))) float;

// ---- W -> MFMA-B fragment layout, f16. 2048 threads, one 16B frag/thread.
// Wf[((ct*4+ks)*64+lane)*8 + j] = W[(ks*32 + (lane>>4)*8 + j)*D + ct*16 + (lane&15)]
__global__ void prep_w(const float* __restrict__ W, _Float16* __restrict__ Wf) {
    int t = blockIdx.x * blockDim.x + threadIdx.x;
    if (t >= 2048) return;
    int ct = t >> 8, ks = (t >> 6) & 3, lane = t & 63;
    int q = lane >> 4, li = lane & 15;
    _Float16 v[8];
    #pragma unroll
    for (int j = 0; j < 8; ++j)
        v[j] = (_Float16)W[(ks * 32 + q * 8 + j) * D + ct * 16 + li];
    *(f16x8*)(Wf + (size_t)t * 8) = *(const f16x8*)v;
}

// ---- fused scatter (even blocks) + MFMA transform (odd blocks) ----
__global__ __launch_bounds__(256) void prep(
        const float* __restrict__ feature,
        const int*   __restrict__ esrc,
        const int*   __restrict__ edst,
        const _Float16* __restrict__ Wf,
        int* __restrict__ cnt,
        unsigned short* __restrict__ bucket,
        _Float16* __restrict__ Z) {
    const int role = blockIdx.x & 1;
    const int bid  = blockIdx.x >> 1;
    const int tid  = threadIdx.x;

    if (role == 0) {
        // scatter: 1024 edges/block, 4/thread, int4 loads
        const int e0 = bid * 1024 + tid * 4;
        if (e0 + 3 < E) {
            const int4 s4 = *(const int4*)(esrc + e0);
            const int4 d4 = *(const int4*)(edst + e0);
            int p;
            p = atomicAdd(&cnt[d4.x], 1); if (p < CAP) bucket[d4.x * CAP + p] = (unsigned short)s4.x;
            p = atomicAdd(&cnt[d4.y], 1); if (p < CAP) bucket[d4.y * CAP + p] = (unsigned short)s4.y;
            p = atomicAdd(&cnt[d4.z], 1); if (p < CAP) bucket[d4.z * CAP + p] = (unsigned short)s4.z;
            p = atomicAdd(&cnt[d4.w], 1); if (p < CAP) bucket[d4.w * CAP + p] = (unsigned short)s4.w;
        } else {
            for (int e = e0; e < E; ++e) {
                int dd = edst[e];
                int p  = atomicAdd(&cnt[dd], 1);
                if (p < CAP) bucket[dd * CAP + p] = (unsigned short)esrc[e];
            }
        }
        return;
    }

    // transform: wave-tile = 16 nodes x 128 cols, 4 waves/block
    __shared__ _Float16 zs[4][16 * ZSTR];
    const int wave = tid >> 6, lane = tid & 63;
    const int wt = bid * 4 + wave;
    if (wt >= NT) return;
    const int q = lane >> 4, li = lane & 15;

    // A-frags: 4 k-steps, 8 consecutive fp32 each, converted to f16
    const float* fp = feature + (size_t)(wt * 16 + li) * D + q * 8;
    f16x8 afr[4];
    #pragma unroll
    for (int ks = 0; ks < 4; ++ks) {
        const float4 u0 = *(const float4*)(fp + ks * 32);
        const float4 u1 = *(const float4*)(fp + ks * 32 + 4);
        afr[ks][0] = (_Float16)u0.x; afr[ks][1] = (_Float16)u0.y;
        afr[ks][2] = (_Float16)u0.z; afr[ks][3] = (_Float16)u0.w;
        afr[ks][4] = (_Float16)u1.x; afr[ks][5] = (_Float16)u1.y;
        afr[ks][6] = (_Float16)u1.z; afr[ks][7] = (_Float16)u1.w;
    }

    f32x4 acc[8];
    #pragma unroll
    for (int ct = 0; ct < 8; ++ct) acc[ct] = (f32x4){0.f, 0.f, 0.f, 0.f};

    #pragma unroll
    for (int ks = 0; ks < 4; ++ks) {
        #pragma unroll
        for (int ct = 0; ct < 8; ++ct) {
            const f16x8 b = *(const f16x8*)(Wf + (size_t)((ct * 4 + ks) * 64 + lane) * 8);
            acc[ct] = __builtin_amdgcn_mfma_f32_16x16x32_f16(afr[ks], b, acc[ct], 0, 0, 0);
        }
    }

    // D (col=li, row=q*4+r) -> LDS (wave-private, no barrier) -> coalesced Z
    _Float16* zt = zs[wave];
    #pragma unroll
    for (int ct = 0; ct < 8; ++ct)
        #pragma unroll
        for (int r = 0; r < 4; ++r)
            zt[(q * 4 + r) * ZSTR + ct * 16 + li] = (_Float16)acc[ct][r];
    #pragma unroll
    for (int it = 0; it < 4; ++it) {
        const f16x8 v = *(const f16x8*)(zt + (it * 4 + q) * ZSTR + li * 8);
        *(f16x8*)(Z + (size_t)(wt * 16 + it * 4 + q) * D + li * 8) = v;
    }
}

// ---- gather: one wave/node; 64 lanes = 4 row-groups x 16 col-lanes ----
__global__ __launch_bounds__(256) void gather(
        const _Float16* __restrict__ Z,
        const int* __restrict__ cnt,
        const unsigned short* __restrict__ bucket,
        const float* __restrict__ bias,
        float* __restrict__ out) {
    const int tid  = threadIdx.x;
    const int wave = tid >> 6, lane = tid & 63;
    const int node = blockIdx.x * 4 + wave;
    const int g    = lane >> 4, li = lane & 15;

    int deg = cnt[node];
    deg = deg > CAP ? CAP : deg;
    const int src = bucket[node * CAP + lane];

    float acc[8] = {0, 0, 0, 0, 0, 0, 0, 0};
    for (int base = 0; base < deg; base += 16) {
        f16x8 h[4];
        float m[4];
        #pragma unroll
        for (int t = 0; t < 4; ++t) {           // 4 independent loads up-front
            const int r = base + t * 4 + g;
            const int s = __shfl(src, min(r, deg - 1));
            m[t] = (r < deg) ? 1.f : 0.f;
            h[t] = *(const f16x8*)(Z + (size_t)s * D + li * 8);
        }
        #pragma unroll
        for (int t = 0; t < 4; ++t)
            #pragma unroll
            for (int j = 0; j < 8; ++j)
                acc[j] += m[t] * (float)h[t][j];
    }

    #pragma unroll
    for (int j = 0; j < 8; ++j) {
        acc[j] += __shfl_xor(acc[j], 16);
        acc[j] += __shfl_xor(acc[j], 32);
    }

    if (g == 0) {
        const float4 b0 = *(const float4*)(bias + li * 8);
        const float4 b1 = *(const float4*)(bias + li * 8 + 4);
        float4 o0, o1;
        o0.x = fmaxf(acc[0] + b0.x, 0.f); o0.y = fmaxf(acc[1] + b0.y, 0.f);
        o0.z = fmaxf(acc[2] + b0.z, 0.f); o0.w = fmaxf(acc[3] + b0.w, 0.f);
        o1.x = fmaxf(acc[4] + b1.x, 0.f); o1.y = fmaxf(acc[5] + b1.y, 0.f);
        o1.z = fmaxf(acc[6] + b1.z, 0.f); o1.w = fmaxf(acc[7] + b1.w, 0.f);
        float* op = out + (size_t)node * D + li * 8;
        *(float4*)op       = o0;
        *(float4*)(op + 4) = o1;
    }
}

extern "C" void kernel_launch(void* const* d_in, const int* in_sizes, int n_in,
                              void* d_out, int out_size, void* d_ws, size_t ws_size,
                              hipStream_t stream) {
    const float* feature = (const float*)d_in[0];
    const int*   esrc    = (const int*)d_in[1];
    const int*   edst    = (const int*)d_in[2];
    const float* W       = (const float*)d_in[3];
    const float* bias    = (const float*)d_in[4];
    float*       out     = (float*)d_out;

    // ws: cnt int[N] | bucket ushort[N*CAP] | Z f16[N*D] | Wf f16[16384]
    int*            cnt    = (int*)d_ws;
    unsigned short* bucket = (unsigned short*)(cnt + N);
    _Float16*       Z      = (_Float16*)(bucket + (size_t)N * CAP);
    _Float16*       Wf     = Z + (size_t)N * D;

    hipMemsetAsync(cnt, 0, N * sizeof(int), stream);
    prep_w<<<8, 256, 0, stream>>>(W, Wf);
    prep<<<1564, 256, 0, stream>>>(feature, esrc, edst, Wf, cnt, bucket, Z);
    gather<<<N / 4, 256, 0, stream>>>(Z, cnt, bucket, bias, out);
}

// Round 4
// 155.525 us; speedup vs baseline: 2.2022x; 1.0119x over previous
//
#include <hip/hip_runtime.h>
#include <hip/hip_fp16.h>

// GCN layer: out = relu(segment_sum(feature[edge_src] by edge_dst) @ W + b)
// Transform-then-aggregate: Z = feature @ W (MFMA f16, fp32 acc), then
// out = relu(segsum(Z[src]) + b).
//
// Pipeline: setup (zero padded cnt + W->frag layout) ->
//   prep [fused: blocks 0..390 scatter edges (8/thread, padded counters),
//         rest MFMA-transform] -> gather (2 nodes/wave, 8 loads in flight).

constexpr int N    = 50000;
constexpr int E    = 800000;
constexpr int D    = 128;
constexpr int CAP  = 64;    // bucket slots/node; Poisson(16) max deg ~45
constexpr int CSTR = 16;    // cnt stride in ints: 1 counter per 64B line
constexpr int NT   = 3125;  // 16-node transform tiles
constexpr int ZSTR = 136;   // LDS f16 row stride (conflict-free)
constexpr int SCB  = 391;   // scatter blocks (8 edges/thread, 256 thr)

using f16x8 = __attribute__((ext_vector_type(8))) _Float16;
using f32x4 = __attribute__((ext_vector_type(4))) float;

// ---- setup: blocks 0..7 build W fragments; rest zero padded cnt ----
// Wf[((ct*4+ks)*64+lane)*8+j] = W[(ks*32+(lane>>4)*8+j)*D + ct*16 + (lane&15)]
__global__ void setup(const float* __restrict__ W, _Float16* __restrict__ Wf,
                      int* __restrict__ cnt) {
    const int tid = threadIdx.x;
    if (blockIdx.x < 8) {
        int t = blockIdx.x * 256 + tid;
        int ct = t >> 8, ks = (t >> 6) & 3, lane = t & 63;
        int q = lane >> 4, li = lane & 15;
        _Float16 v[8];
        #pragma unroll
        for (int j = 0; j < 8; ++j)
            v[j] = (_Float16)W[(ks * 32 + q * 8 + j) * D + ct * 16 + li];
        *(f16x8*)(Wf + (size_t)t * 8) = *(const f16x8*)v;
    } else {
        int i4 = (blockIdx.x - 8) * 256 + tid;      // int4 index
        if (i4 < N * CSTR / 4)
            ((int4*)cnt)[i4] = make_int4(0, 0, 0, 0);
    }
}

// ---- fused scatter + MFMA transform ----
__global__ __launch_bounds__(256) void prep(
        const float* __restrict__ feature,
        const int*   __restrict__ esrc,
        const int*   __restrict__ edst,
        const _Float16* __restrict__ Wf,
        int* __restrict__ cnt,
        unsigned short* __restrict__ bucket,
        _Float16* __restrict__ Z) {
    const int tid = threadIdx.x;

    if (blockIdx.x < SCB) {
        // scatter: 8 edges/thread; batch the 8 independent atomics first
        const int t = blockIdx.x * 256 + tid;
        if (t * 8 >= E) return;
        const int e0 = t * 8;
        const int4 s0 = *(const int4*)(esrc + e0);
        const int4 s1 = *(const int4*)(esrc + e0 + 4);
        const int4 d0 = *(const int4*)(edst + e0);
        const int4 d1 = *(const int4*)(edst + e0 + 4);
        const int ds[8] = {d0.x, d0.y, d0.z, d0.w, d1.x, d1.y, d1.z, d1.w};
        const int ss[8] = {s0.x, s0.y, s0.z, s0.w, s1.x, s1.y, s1.z, s1.w};
        int ps[8];
        #pragma unroll
        for (int j = 0; j < 8; ++j)
            ps[j] = atomicAdd(&cnt[ds[j] * CSTR], 1);
        #pragma unroll
        for (int j = 0; j < 8; ++j)
            if (ps[j] < CAP)
                bucket[ds[j] * CAP + ps[j]] = (unsigned short)ss[j];
        return;
    }

    // transform: wave-tile = 16 nodes x 128 cols
    __shared__ _Float16 zs[4][16 * ZSTR];
    const int wave = tid >> 6, lane = tid & 63;
    const int wt = (blockIdx.x - SCB) * 4 + wave;
    if (wt >= NT) return;
    const int q = lane >> 4, li = lane & 15;

    const float* fp = feature + (size_t)(wt * 16 + li) * D + q * 8;
    f16x8 afr[4];
    #pragma unroll
    for (int ks = 0; ks < 4; ++ks) {
        const float4 u0 = *(const float4*)(fp + ks * 32);
        const float4 u1 = *(const float4*)(fp + ks * 32 + 4);
        afr[ks][0] = (_Float16)u0.x; afr[ks][1] = (_Float16)u0.y;
        afr[ks][2] = (_Float16)u0.z; afr[ks][3] = (_Float16)u0.w;
        afr[ks][4] = (_Float16)u1.x; afr[ks][5] = (_Float16)u1.y;
        afr[ks][6] = (_Float16)u1.z; afr[ks][7] = (_Float16)u1.w;
    }

    f32x4 acc[8];
    #pragma unroll
    for (int ct = 0; ct < 8; ++ct) acc[ct] = (f32x4){0.f, 0.f, 0.f, 0.f};
    #pragma unroll
    for (int ks = 0; ks < 4; ++ks)
        #pragma unroll
        for (int ct = 0; ct < 8; ++ct) {
            const f16x8 b = *(const f16x8*)(Wf + (size_t)((ct * 4 + ks) * 64 + lane) * 8);
            acc[ct] = __builtin_amdgcn_mfma_f32_16x16x32_f16(afr[ks], b, acc[ct], 0, 0, 0);
        }

    // D (col=li, row=q*4+r) -> wave-private LDS -> coalesced 16B Z stores
    _Float16* zt = zs[wave];
    #pragma unroll
    for (int ct = 0; ct < 8; ++ct)
        #pragma unroll
        for (int r = 0; r < 4; ++r)
            zt[(q * 4 + r) * ZSTR + ct * 16 + li] = (_Float16)acc[ct][r];
    #pragma unroll
    for (int it = 0; it < 4; ++it) {
        const f16x8 v = *(const f16x8*)(zt + (it * 4 + q) * ZSTR + li * 8);
        *(f16x8*)(Z + (size_t)(wt * 16 + it * 4 + q) * D + li * 8) = v;
    }
}

// ---- gather: 2 nodes per wave, 8 independent Z loads in flight ----
__global__ __launch_bounds__(256) void gather(
        const _Float16* __restrict__ Z,
        const int* __restrict__ cnt,
        const unsigned short* __restrict__ bucket,
        const float* __restrict__ bias,
        float* __restrict__ out) {
    const int tid  = threadIdx.x;
    const int wave = tid >> 6, lane = tid & 63;
    const int g    = lane >> 4, li = lane & 15;
    const int nA   = blockIdx.x * 8 + wave * 2;
    const int nB   = nA + 1;

    const int degA = min(cnt[nA * CSTR], CAP);
    const int degB = min(cnt[nB * CSTR], CAP);
    const int srcA = bucket[nA * CAP + lane];
    const int srcB = bucket[nB * CAP + lane];
    const float4 b0 = *(const float4*)(bias + li * 8);
    const float4 b1 = *(const float4*)(bias + li * 8 + 4);

    float accA[8] = {0,0,0,0,0,0,0,0};
    float accB[8] = {0,0,0,0,0,0,0,0};

    const int mx = max(degA, degB);
    for (int base = 0; base < mx; base += 16) {
        f16x8 hA[4], hB[4];
        float mA[4], mB[4];
        #pragma unroll
        for (int t = 0; t < 4; ++t) {        // 8 independent loads
            const int r  = base + t * 4 + g;
            const int sA = __shfl(srcA, min(r, max(degA - 1, 0)));
            const int sB = __shfl(srcB, min(r, max(degB - 1, 0)));
            mA[t] = (r < degA) ? 1.f : 0.f;
            mB[t] = (r < degB) ? 1.f : 0.f;
            hA[t] = *(const f16x8*)(Z + (size_t)sA * D + li * 8);
            hB[t] = *(const f16x8*)(Z + (size_t)sB * D + li * 8);
        }
        #pragma unroll
        for (int t = 0; t < 4; ++t)
            #pragma unroll
            for (int j = 0; j < 8; ++j) {
                accA[j] += mA[t] * (float)hA[t][j];
                accB[j] += mB[t] * (float)hB[t][j];
            }
    }

    #pragma unroll
    for (int j = 0; j < 8; ++j) {
        accA[j] += __shfl_xor(accA[j], 16);
        accA[j] += __shfl_xor(accA[j], 32);
        accB[j] += __shfl_xor(accB[j], 16);
        accB[j] += __shfl_xor(accB[j], 32);
    }

    if (g == 0) {
        float4 o0, o1;
        o0.x = fmaxf(accA[0] + b0.x, 0.f); o0.y = fmaxf(accA[1] + b0.y, 0.f);
        o0.z = fmaxf(accA[2] + b0.z, 0.f); o0.w = fmaxf(accA[3] + b0.w, 0.f);
        o1.x = fmaxf(accA[4] + b1.x, 0.f); o1.y = fmaxf(accA[5] + b1.y, 0.f);
        o1.z = fmaxf(accA[6] + b1.z, 0.f); o1.w = fmaxf(accA[7] + b1.w, 0.f);
        float* op = out + (size_t)nA * D + li * 8;
        *(float4*)op       = o0;
        *(float4*)(op + 4) = o1;
    } else if (g == 1) {
        float4 o0, o1;
        o0.x = fmaxf(accB[0] + b0.x, 0.f); o0.y = fmaxf(accB[1] + b0.y, 0.f);
        o0.z = fmaxf(accB[2] + b0.z, 0.f); o0.w = fmaxf(accB[3] + b0.w, 0.f);
        o1.x = fmaxf(accB[4] + b1.x, 0.f); o1.y = fmaxf(accB[5] + b1.y, 0.f);
        o1.z = fmaxf(accB[6] + b1.z, 0.f); o1.w = fmaxf(accB[7] + b1.w, 0.f);
        float* op = out + (size_t)nB * D + li * 8;
        *(float4*)op       = o0;
        *(float4*)(op + 4) = o1;
    }
}

extern "C" void kernel_launch(void* const* d_in, const int* in_sizes, int n_in,
                              void* d_out, int out_size, void* d_ws, size_t ws_size,
                              hipStream_t stream) {
    const float* feature = (const float*)d_in[0];
    const int*   esrc    = (const int*)d_in[1];
    const int*   edst    = (const int*)d_in[2];
    const float* W       = (const float*)d_in[3];
    const float* bias    = (const float*)d_in[4];
    float*       out     = (float*)d_out;

    // ws: cnt int[N*CSTR] (3.2MB) | bucket ushort[N*CAP] (6.4MB) |
    //     Z f16[N*D] (12.8MB) | Wf f16[16384] (32KB)
    int*            cnt    = (int*)d_ws;
    unsigned short* bucket = (unsigned short*)(cnt + (size_t)N * CSTR);
    _Float16*       Z      = (_Float16*)(bucket + (size_t)N * CAP);
    _Float16*       Wf     = Z + (size_t)N * D;

    setup<<<8 + (N * CSTR / 4 + 255) / 256, 256, 0, stream>>>(W, Wf, cnt);
    prep<<<SCB + (NT + 3) / 4, 256, 0, stream>>>(feature, esrc, edst, Wf, cnt, bucket, Z);
    gather<<<N / 8, 256, 0, stream>>>(Z, cnt, bucket, bias, out);
}

// Round 5
// 151.978 us; speedup vs baseline: 2.2536x; 1.0233x over previous
//
#include <hip/hip_runtime.h>
#include <hip/hip_fp16.h>

// GCN layer: out = relu(segment_sum(feature[edge_src] by edge_dst) @ W + b)
// Transform-then-aggregate: Z = feature @ W (MFMA f16, fp32 acc), then
// out = relu(segsum(Z[src]) + b).
//
// CSR build is a 2-pass LDS counting sort (NO contended global atomics --
// device atomics execute at the non-coherent-L2 coherence point and cap at
// ~17 G/s, which was the round-4 bottleneck):
//   setup  : W -> MFMA-B fragment layout
//   midk   : [fused] 256 blocks LDS-histogram dst>>8 ranges | 782 blocks MFMA
//   scank  : per-range exclusive scan over block counts
//   partk  : rank via LDS atomics, write dst-partitioned packed edges
//   csrk   : per-range LDS slotting -> bucket[node*CAP], exact cnt[node]
//   gather : 2 nodes/wave, 8 x 16B Z loads in flight

constexpr int N    = 50000;
constexpr int E    = 800000;
constexpr int D    = 128;
constexpr int CAP  = 64;     // bucket slots/node; Poisson(16) max deg ~45
constexpr int NT   = 3125;   // 16-node transform tiles
constexpr int ZSTR = 136;    // LDS f16 row stride (conflict-free)
constexpr int NR   = 196;    // dst ranges: range = dst>>8 (50000>>8 = 195)
constexpr int HB   = 256;    // histogram/partition blocks
constexpr int EPB  = E / HB; // 3125 edges per block (exact)

using f16x8 = __attribute__((ext_vector_type(8))) _Float16;
using f32x4 = __attribute__((ext_vector_type(4))) float;

// ---- setup: W -> MFMA-B fragment layout (8 blocks x 256) ----
// Wf[((ct*4+ks)*64+lane)*8+j] = W[(ks*32+(lane>>4)*8+j)*D + ct*16 + (lane&15)]
__global__ void setup(const float* __restrict__ W, _Float16* __restrict__ Wf) {
    int t = blockIdx.x * 256 + threadIdx.x;
    int ct = t >> 8, ks = (t >> 6) & 3, lane = t & 63;
    int q = lane >> 4, li = lane & 15;
    _Float16 v[8];
    #pragma unroll
    for (int j = 0; j < 8; ++j)
        v[j] = (_Float16)W[(ks * 32 + q * 8 + j) * D + ct * 16 + li];
    *(f16x8*)(Wf + (size_t)t * 8) = *(const f16x8*)v;
}

// ---- fused: blocks 0..255 LDS histogram; rest MFMA transform ----
__global__ __launch_bounds__(256) void midk(
        const float* __restrict__ feature,
        const int*   __restrict__ edst,
        const _Float16* __restrict__ Wf,
        int* __restrict__ hist,          // [HB][NR]
        _Float16* __restrict__ Z) {
    __shared__ int h[NR];
    __shared__ _Float16 zs[4][16 * ZSTR];
    const int tid = threadIdx.x;

    if (blockIdx.x < HB) {
        const int b = blockIdx.x;
        if (tid < NR) h[tid] = 0;
        __syncthreads();
        const int e0 = b * EPB;
        for (int i = tid; i < EPB; i += 256)
            atomicAdd(&h[edst[e0 + i] >> 8], 1);
        __syncthreads();
        if (tid < NR) hist[b * NR + tid] = h[tid];
        return;
    }

    // transform: wave-tile = 16 nodes x 128 cols
    const int wave = tid >> 6, lane = tid & 63;
    const int wt = (blockIdx.x - HB) * 4 + wave;
    if (wt >= NT) return;
    const int q = lane >> 4, li = lane & 15;

    const float* fp = feature + (size_t)(wt * 16 + li) * D + q * 8;
    f16x8 afr[4];
    #pragma unroll
    for (int ks = 0; ks < 4; ++ks) {
        const float4 u0 = *(const float4*)(fp + ks * 32);
        const float4 u1 = *(const float4*)(fp + ks * 32 + 4);
        afr[ks][0] = (_Float16)u0.x; afr[ks][1] = (_Float16)u0.y;
        afr[ks][2] = (_Float16)u0.z; afr[ks][3] = (_Float16)u0.w;
        afr[ks][4] = (_Float16)u1.x; afr[ks][5] = (_Float16)u1.y;
        afr[ks][6] = (_Float16)u1.z; afr[ks][7] = (_Float16)u1.w;
    }

    f32x4 acc[8];
    #pragma unroll
    for (int ct = 0; ct < 8; ++ct) acc[ct] = (f32x4){0.f, 0.f, 0.f, 0.f};
    #pragma unroll
    for (int ks = 0; ks < 4; ++ks)
        #pragma unroll
        for (int ct = 0; ct < 8; ++ct) {
            const f16x8 b = *(const f16x8*)(Wf + (size_t)((ct * 4 + ks) * 64 + lane) * 8);
            acc[ct] = __builtin_amdgcn_mfma_f32_16x16x32_f16(afr[ks], b, acc[ct], 0, 0, 0);
        }

    _Float16* zt = zs[wave];
    #pragma unroll
    for (int ct = 0; ct < 8; ++ct)
        #pragma unroll
        for (int r = 0; r < 4; ++r)
            zt[(q * 4 + r) * ZSTR + ct * 16 + li] = (_Float16)acc[ct][r];
    #pragma unroll
    for (int it = 0; it < 4; ++it) {
        const f16x8 v = *(const f16x8*)(zt + (it * 4 + q) * ZSTR + li * 8);
        *(f16x8*)(Z + (size_t)(wt * 16 + it * 4 + q) * D + li * 8) = v;
    }
}

// ---- scank: per range r, exclusive scan of hist[b][r] over b ----
__global__ void scank(int* __restrict__ hist, int* __restrict__ total) {
    const int r    = blockIdx.x;   // 0..NR-1
    const int lane = threadIdx.x;  // 0..63
    int h[4], sum = 0;
    #pragma unroll
    for (int j = 0; j < 4; ++j) {
        h[j] = hist[(lane * 4 + j) * NR + r];
        sum += h[j];
    }
    int incl = sum;
    #pragma unroll
    for (int off = 1; off < 64; off <<= 1) {
        int u = __shfl_up(incl, off);
        if (lane >= off) incl += u;
    }
    int run = incl - sum;          // exclusive
    #pragma unroll
    for (int j = 0; j < 4; ++j) {
        hist[(lane * 4 + j) * NR + r] = run;   // becomes blockBase
        run += h[j];
    }
    if (lane == 63) total[r] = run;
}

// ---- partk: write dst-partitioned packed edges ----
__global__ __launch_bounds__(256) void partk(
        const int* __restrict__ esrc,
        const int* __restrict__ edst,
        const int* __restrict__ blockBase,   // [HB][NR]
        const int* __restrict__ total,       // [NR]
        int* __restrict__ rangeStartG,       // [NR] (written by block 0)
        unsigned int* __restrict__ part) {
    __shared__ int rs[NR];
    __shared__ int mb[NR];
    __shared__ int rk[NR];
    const int tid = threadIdx.x;
    const int b   = blockIdx.x;

    if (tid < 64) {                 // wave 0: exclusive scan of totals
        int carry = 0;
        #pragma unroll
        for (int c = 0; c < 4; ++c) {
            int idx = c * 64 + tid;
            int v = (idx < NR) ? total[idx] : 0;
            int incl = v;
            #pragma unroll
            for (int off = 1; off < 64; off <<= 1) {
                int u = __shfl_up(incl, off);
                if (tid >= off) incl += u;
            }
            if (idx < NR) rs[idx] = incl - v + carry;
            carry += __shfl(incl, 63);
        }
    }
    if (tid < NR) { mb[tid] = blockBase[b * NR + tid]; rk[tid] = 0; }
    __syncthreads();
    if (b == 0 && tid < NR) rangeStartG[tid] = rs[tid];

    const int e0 = b * EPB;
    for (int i = tid; i < EPB; i += 256) {
        const int s = esrc[e0 + i];
        const int d = edst[e0 + i];
        const int r = d >> 8;
        const int k = atomicAdd(&rk[r], 1);          // LDS atomic
        part[rs[r] + mb[r] + k] = ((unsigned)(d & 255) << 16) | (unsigned)s;
    }
}

// ---- csrk: block r owns nodes r*256..+255; build bucket + cnt ----
__global__ __launch_bounds__(256) void csrk(
        const unsigned int* __restrict__ part,
        const int* __restrict__ rangeStart,
        const int* __restrict__ total,
        unsigned short* __restrict__ bucket,
        int* __restrict__ cnt) {
    __shared__ int deg[256];
    const int r = blockIdx.x, tid = threadIdx.x;
    deg[tid] = 0;
    __syncthreads();
    const int rs = rangeStart[r], tot = total[r];
    for (int i = tid; i < tot; i += 256) {
        const unsigned p = part[rs + i];
        const int local = p >> 16;
        const int src   = p & 0xFFFF;
        const int k = atomicAdd(&deg[local], 1);     // LDS atomic
        if (k < CAP)
            bucket[(((size_t)r << 8) + local) * CAP + k] = (unsigned short)src;
    }
    __syncthreads();
    const int node = (r << 8) + tid;
    if (node < N) cnt[node] = deg[tid];
}

// ---- gather: 2 nodes per wave, 8 independent Z loads in flight ----
__global__ __launch_bounds__(256) void gather(
        const _Float16* __restrict__ Z,
        const int* __restrict__ cnt,
        const unsigned short* __restrict__ bucket,
        const float* __restrict__ bias,
        float* __restrict__ out) {
    const int tid  = threadIdx.x;
    const int wave = tid >> 6, lane = tid & 63;
    const int g    = lane >> 4, li = lane & 15;
    const int nA   = blockIdx.x * 8 + wave * 2;
    const int nB   = nA + 1;

    const int degA = min(cnt[nA], CAP);
    const int degB = min(cnt[nB], CAP);
    const int srcA = bucket[nA * CAP + lane];
    const int srcB = bucket[nB * CAP + lane];
    const float4 b0 = *(const float4*)(bias + li * 8);
    const float4 b1 = *(const float4*)(bias + li * 8 + 4);

    float accA[8] = {0,0,0,0,0,0,0,0};
    float accB[8] = {0,0,0,0,0,0,0,0};

    const int mx = max(degA, degB);
    for (int base = 0; base < mx; base += 16) {
        f16x8 hA[4], hB[4];
        float mA[4], mB[4];
        #pragma unroll
        for (int t = 0; t < 4; ++t) {        // 8 independent loads
            const int r  = base + t * 4 + g;
            const int sA = __shfl(srcA, min(r, max(degA - 1, 0)));
            const int sB = __shfl(srcB, min(r, max(degB - 1, 0)));
            mA[t] = (r < degA) ? 1.f : 0.f;
            mB[t] = (r < degB) ? 1.f : 0.f;
            hA[t] = *(const f16x8*)(Z + (size_t)sA * D + li * 8);
            hB[t] = *(const f16x8*)(Z + (size_t)sB * D + li * 8);
        }
        #pragma unroll
        for (int t = 0; t < 4; ++t)
            #pragma unroll
            for (int j = 0; j < 8; ++j) {
                accA[j] += mA[t] * (float)hA[t][j];
                accB[j] += mB[t] * (float)hB[t][j];
            }
    }

    #pragma unroll
    for (int j = 0; j < 8; ++j) {
        accA[j] += __shfl_xor(accA[j], 16);
        accA[j] += __shfl_xor(accA[j], 32);
        accB[j] += __shfl_xor(accB[j], 16);
        accB[j] += __shfl_xor(accB[j], 32);
    }

    if (g == 0) {
        float4 o0, o1;
        o0.x = fmaxf(accA[0] + b0.x, 0.f); o0.y = fmaxf(accA[1] + b0.y, 0.f);
        o0.z = fmaxf(accA[2] + b0.z, 0.f); o0.w = fmaxf(accA[3] + b0.w, 0.f);
        o1.x = fmaxf(accA[4] + b1.x, 0.f); o1.y = fmaxf(accA[5] + b1.y, 0.f);
        o1.z = fmaxf(accA[6] + b1.z, 0.f); o1.w = fmaxf(accA[7] + b1.w, 0.f);
        float* op = out + (size_t)nA * D + li * 8;
        *(float4*)op       = o0;
        *(float4*)(op + 4) = o1;
    } else if (g == 1) {
        float4 o0, o1;
        o0.x = fmaxf(accB[0] + b0.x, 0.f); o0.y = fmaxf(accB[1] + b0.y, 0.f);
        o0.z = fmaxf(accB[2] + b0.z, 0.f); o0.w = fmaxf(accB[3] + b0.w, 0.f);
        o1.x = fmaxf(accB[4] + b1.x, 0.f); o1.y = fmaxf(accB[5] + b1.y, 0.f);
        o1.z = fmaxf(accB[6] + b1.z, 0.f); o1.w = fmaxf(accB[7] + b1.w, 0.f);
        float* op = out + (size_t)nB * D + li * 8;
        *(float4*)op       = o0;
        *(float4*)(op + 4) = o1;
    }
}

extern "C" void kernel_launch(void* const* d_in, const int* in_sizes, int n_in,
                              void* d_out, int out_size, void* d_ws, size_t ws_size,
                              hipStream_t stream) {
    const float* feature = (const float*)d_in[0];
    const int*   esrc    = (const int*)d_in[1];
    const int*   edst    = (const int*)d_in[2];
    const float* W       = (const float*)d_in[3];
    const float* bias    = (const float*)d_in[4];
    float*       out     = (float*)d_out;

    // ws: cnt int[N] | bucket ushort[N*CAP] | Z f16[N*D] | Wf f16[16384] |
    //     hist int[HB*NR] | total int[NR] | rangeStart int[NR] | part uint[E]
    int*            cnt    = (int*)d_ws;
    unsigned short* bucket = (unsigned short*)(cnt + N);
    _Float16*       Z      = (_Float16*)(bucket + (size_t)N * CAP);
    _Float16*       Wf     = Z + (size_t)N * D;
    int*            hist   = (int*)(Wf + 16384);
    int*            total  = hist + HB * NR;
    int*            rangeS = total + NR;
    unsigned int*   part   = (unsigned int*)(rangeS + NR);

    setup<<<8, 256, 0, stream>>>(W, Wf);
    midk <<<HB + (NT + 3) / 4, 256, 0, stream>>>(feature, edst, Wf, hist, Z);
    scank<<<NR, 64, 0, stream>>>(hist, total);
    partk<<<HB, 256, 0, stream>>>(esrc, edst, hist, total, rangeS, part);
    csrk <<<NR, 256, 0, stream>>>(part, rangeS, total, bucket, cnt);
    gather<<<N / 8, 256, 0, stream>>>(Z, cnt, bucket, bias, out);
}

// Round 6
// 145.135 us; speedup vs baseline: 2.3598x; 1.0471x over previous
//
#include <hip/hip_runtime.h>
#include <hip/hip_fp16.h>

// GCN layer: out = relu(segment_sum(feature[edge_src] by edge_dst) @ W + b)
// Transform-then-aggregate: Z = feature @ W (MFMA f16, fp32 acc), then
// out = relu(segsum(Z[src]) + b).
//
// CSR build is an LDS counting sort at 64-node granularity (dst>>6) so the
// partitioned edge span of one range == one gather block's tile:
//   setup     : W -> MFMA-B fragment layout; Z[N] = zero row
//   midk      : [fused] 500 blocks LDS-histogram dst>>6 | 782 blocks MFMA
//   scank     : per-range exclusive scan over block counts
//   partk     : rank via LDS atomics, write dst-partitioned packed edges
//   csrgather : per-range LDS bucket build + register-accumulate gather
// No contended global atomics anywhere (round-4 lesson: device atomics
// serialize at the non-coherent-L2 coherence point, ~17 G/s).

constexpr int N    = 50000;
constexpr int E    = 800000;
constexpr int D    = 128;
constexpr int CAP  = 64;      // bucket slots/node; Poisson(16) max deg ~45
constexpr int NT   = 3125;    // 16-node transform tiles
constexpr int ZSTR = 136;     // LDS f16 row stride (conflict-free)
constexpr int NR   = 782;     // dst ranges: range = dst>>6 (49999>>6 = 781)
constexpr int HB   = 500;     // histogram/partition blocks
constexpr int EPB  = E / HB;  // 1600 edges per block (exact)

using f16x8 = __attribute__((ext_vector_type(8))) _Float16;
using f32x4 = __attribute__((ext_vector_type(4))) float;

// ---- setup: blocks 0..7 W->frag layout; block 8 zeroes Z's sentinel row --
// Wf[((ct*4+ks)*64+lane)*8+j] = W[(ks*32+(lane>>4)*8+j)*D + ct*16 + (lane&15)]
__global__ void setup(const float* __restrict__ W, _Float16* __restrict__ Wf,
                      _Float16* __restrict__ Z) {
    if (blockIdx.x == 8) {
        if (threadIdx.x < D) Z[(size_t)N * D + threadIdx.x] = (_Float16)0.f;
        return;
    }
    int t = blockIdx.x * 256 + threadIdx.x;
    int ct = t >> 8, ks = (t >> 6) & 3, lane = t & 63;
    int q = lane >> 4, li = lane & 15;
    _Float16 v[8];
    #pragma unroll
    for (int j = 0; j < 8; ++j)
        v[j] = (_Float16)W[(ks * 32 + q * 8 + j) * D + ct * 16 + li];
    *(f16x8*)(Wf + (size_t)t * 8) = *(const f16x8*)v;
}

// ---- fused: blocks 0..HB-1 LDS histogram; rest MFMA transform ----
__global__ __launch_bounds__(256) void midk(
        const float* __restrict__ feature,
        const int*   __restrict__ edst,
        const _Float16* __restrict__ Wf,
        int* __restrict__ hist,          // [HB][NR]
        _Float16* __restrict__ Z) {
    __shared__ int h[NR];
    __shared__ _Float16 zs[4][16 * ZSTR];
    const int tid = threadIdx.x;

    if (blockIdx.x < HB) {
        const int b = blockIdx.x;
        for (int i = tid; i < NR; i += 256) h[i] = 0;
        __syncthreads();
        const int e0 = b * EPB;
        for (int i = tid; i < EPB; i += 256)
            atomicAdd(&h[edst[e0 + i] >> 6], 1);
        __syncthreads();
        for (int i = tid; i < NR; i += 256) hist[b * NR + i] = h[i];
        return;
    }

    // transform: wave-tile = 16 nodes x 128 cols
    const int wave = tid >> 6, lane = tid & 63;
    const int wt = (blockIdx.x - HB) * 4 + wave;
    if (wt >= NT) return;
    const int q = lane >> 4, li = lane & 15;

    const float* fp = feature + (size_t)(wt * 16 + li) * D + q * 8;
    f16x8 afr[4];
    #pragma unroll
    for (int ks = 0; ks < 4; ++ks) {
        const float4 u0 = *(const float4*)(fp + ks * 32);
        const float4 u1 = *(const float4*)(fp + ks * 32 + 4);
        afr[ks][0] = (_Float16)u0.x; afr[ks][1] = (_Float16)u0.y;
        afr[ks][2] = (_Float16)u0.z; afr[ks][3] = (_Float16)u0.w;
        afr[ks][4] = (_Float16)u1.x; afr[ks][5] = (_Float16)u1.y;
        afr[ks][6] = (_Float16)u1.z; afr[ks][7] = (_Float16)u1.w;
    }

    f32x4 acc[8];
    #pragma unroll
    for (int ct = 0; ct < 8; ++ct) acc[ct] = (f32x4){0.f, 0.f, 0.f, 0.f};
    #pragma unroll
    for (int ks = 0; ks < 4; ++ks)
        #pragma unroll
        for (int ct = 0; ct < 8; ++ct) {
            const f16x8 b = *(const f16x8*)(Wf + (size_t)((ct * 4 + ks) * 64 + lane) * 8);
            acc[ct] = __builtin_amdgcn_mfma_f32_16x16x32_f16(afr[ks], b, acc[ct], 0, 0, 0);
        }

    _Float16* zt = zs[wave];
    #pragma unroll
    for (int ct = 0; ct < 8; ++ct)
        #pragma unroll
        for (int r = 0; r < 4; ++r)
            zt[(q * 4 + r) * ZSTR + ct * 16 + li] = (_Float16)acc[ct][r];
    #pragma unroll
    for (int it = 0; it < 4; ++it) {
        const f16x8 v = *(const f16x8*)(zt + (it * 4 + q) * ZSTR + li * 8);
        *(f16x8*)(Z + (size_t)(wt * 16 + it * 4 + q) * D + li * 8) = v;
    }
}

// ---- scank: per range r, exclusive scan of hist[b][r] over b ----
__global__ void scank(int* __restrict__ hist, int* __restrict__ total) {
    const int r    = blockIdx.x;   // 0..NR-1
    const int lane = threadIdx.x;  // 0..63
    int h[8], sum = 0;
    #pragma unroll
    for (int j = 0; j < 8; ++j) {
        const int idx = lane * 8 + j;
        h[j] = (idx < HB) ? hist[idx * NR + r] : 0;
        sum += h[j];
    }
    int incl = sum;
    #pragma unroll
    for (int off = 1; off < 64; off <<= 1) {
        int u = __shfl_up(incl, off);
        if (lane >= off) incl += u;
    }
    int run = incl - sum;          // exclusive
    #pragma unroll
    for (int j = 0; j < 8; ++j) {
        const int idx = lane * 8 + j;
        if (idx < HB) hist[idx * NR + r] = run;   // becomes blockBase
        run += h[j];
    }
    if (lane == 63) total[r] = run;
}

// ---- partk: write dst-partitioned packed edges (local6 <<16 | src16) ----
__global__ __launch_bounds__(256) void partk(
        const int* __restrict__ esrc,
        const int* __restrict__ edst,
        const int* __restrict__ blockBase,   // [HB][NR]
        const int* __restrict__ total,       // [NR]
        int* __restrict__ rangeStartG,       // [NR] (written by block 0)
        unsigned int* __restrict__ part) {
    __shared__ int rs[NR];
    __shared__ int mb[NR];
    __shared__ int rk[NR];
    const int tid = threadIdx.x;
    const int b   = blockIdx.x;

    if (tid < 64) {                 // wave 0: exclusive scan of totals
        int carry = 0;
        #pragma unroll
        for (int c = 0; c < 13; ++c) {
            const int idx = c * 64 + tid;
            const int v = (idx < NR) ? total[idx] : 0;
            int incl = v;
            #pragma unroll
            for (int off = 1; off < 64; off <<= 1) {
                int u = __shfl_up(incl, off);
                if (tid >= off) incl += u;
            }
            if (idx < NR) rs[idx] = incl - v + carry;
            carry += __shfl(incl, 63);
        }
    }
    for (int i = tid; i < NR; i += 256) { mb[i] = blockBase[b * NR + i]; rk[i] = 0; }
    __syncthreads();
    if (b == 0)
        for (int i = tid; i < NR; i += 256) rangeStartG[i] = rs[i];

    const int e0 = b * EPB;
    for (int i = tid; i < EPB; i += 256) {
        const int s = esrc[e0 + i];
        const int d = edst[e0 + i];
        const int r = d >> 6;
        const int k = atomicAdd(&rk[r], 1);          // LDS atomic
        part[rs[r] + mb[r] + k] = ((unsigned)(d & 63) << 16) | (unsigned)s;
    }
}

// ---- csrgather: block r owns 64 nodes; LDS bucket + register gather ----
__global__ __launch_bounds__(256) void csrgather(
        const unsigned int* __restrict__ part,
        const int* __restrict__ rangeStart,
        const int* __restrict__ total,
        const _Float16* __restrict__ Z,
        const float* __restrict__ bias,
        float* __restrict__ out) {
    __shared__ unsigned short bkt[64 * CAP];   // 8 KB
    __shared__ int deg[64];
    const int r = blockIdx.x, tid = threadIdx.x;

    if (tid < 64) deg[tid] = 0;
    __syncthreads();
    const int rsv = rangeStart[r], tot = total[r];
    for (int i = tid; i < tot; i += 256) {
        const unsigned p = part[rsv + i];
        const int local = p >> 16;
        const int src   = p & 0xFFFF;
        const int k = atomicAdd(&deg[local], 1);     // LDS atomic
        if (k < CAP) bkt[local * CAP + k] = (unsigned short)src;
    }
    __syncthreads();

    // gather: wave w handles nodes w*16..+15 as 8 pairs, src from LDS;
    // out-of-degree slots read Z's zero sentinel row (index N) -> no masks.
    const int wave = tid >> 6, lane = tid & 63;
    const int g = lane >> 4, li = lane & 15;
    const float4 b0 = *(const float4*)(bias + li * 8);
    const float4 b1 = *(const float4*)(bias + li * 8 + 4);

    for (int pair = 0; pair < 8; ++pair) {
        const int lA = wave * 16 + pair * 2;
        const int lB = lA + 1;
        const int degA = min(deg[lA], CAP);
        const int degB = min(deg[lB], CAP);

        float accA[8] = {0,0,0,0,0,0,0,0};
        float accB[8] = {0,0,0,0,0,0,0,0};

        const int mx = max(degA, degB);
        for (int base = 0; base < mx; base += 16) {
            f16x8 hA[4], hB[4];
            #pragma unroll
            for (int t = 0; t < 4; ++t) {            // 8 independent loads
                const int rr = base + t * 4 + g;     // rr <= 63 < CAP
                int sA = bkt[lA * CAP + rr];         // 16-lane LDS broadcast
                int sB = bkt[lB * CAP + rr];
                sA = (rr < degA) ? sA : N;           // sentinel zero row
                sB = (rr < degB) ? sB : N;
                hA[t] = *(const f16x8*)(Z + (size_t)sA * D + li * 8);
                hB[t] = *(const f16x8*)(Z + (size_t)sB * D + li * 8);
            }
            #pragma unroll
            for (int t = 0; t < 4; ++t)
                #pragma unroll
                for (int j = 0; j < 8; ++j) {
                    accA[j] += (float)hA[t][j];
                    accB[j] += (float)hB[t][j];
                }
        }

        #pragma unroll
        for (int j = 0; j < 8; ++j) {
            accA[j] += __shfl_xor(accA[j], 16);
            accA[j] += __shfl_xor(accA[j], 32);
            accB[j] += __shfl_xor(accB[j], 16);
            accB[j] += __shfl_xor(accB[j], 32);
        }

        const int nodeA = (r << 6) + lA;
        const int nodeB = (r << 6) + lB;
        if (g == 0 && nodeA < N) {
            float4 o0, o1;
            o0.x = fmaxf(accA[0] + b0.x, 0.f); o0.y = fmaxf(accA[1] + b0.y, 0.f);
            o0.z = fmaxf(accA[2] + b0.z, 0.f); o0.w = fmaxf(accA[3] + b0.w, 0.f);
            o1.x = fmaxf(accA[4] + b1.x, 0.f); o1.y = fmaxf(accA[5] + b1.y, 0.f);
            o1.z = fmaxf(accA[6] + b1.z, 0.f); o1.w = fmaxf(accA[7] + b1.w, 0.f);
            float* op = out + (size_t)nodeA * D + li * 8;
            *(float4*)op       = o0;
            *(float4*)(op + 4) = o1;
        } else if (g == 1 && nodeB < N) {
            float4 o0, o1;
            o0.x = fmaxf(accB[0] + b0.x, 0.f); o0.y = fmaxf(accB[1] + b0.y, 0.f);
            o0.z = fmaxf(accB[2] + b0.z, 0.f); o0.w = fmaxf(accB[3] + b0.w, 0.f);
            o1.x = fmaxf(accB[4] + b1.x, 0.f); o1.y = fmaxf(accB[5] + b1.y, 0.f);
            o1.z = fmaxf(accB[6] + b1.z, 0.f); o1.w = fmaxf(accB[7] + b1.w, 0.f);
            float* op = out + (size_t)nodeB * D + li * 8;
            *(float4*)op       = o0;
            *(float4*)(op + 4) = o1;
        }
    }
}

extern "C" void kernel_launch(void* const* d_in, const int* in_sizes, int n_in,
                              void* d_out, int out_size, void* d_ws, size_t ws_size,
                              hipStream_t stream) {
    const float* feature = (const float*)d_in[0];
    const int*   esrc    = (const int*)d_in[1];
    const int*   edst    = (const int*)d_in[2];
    const float* W       = (const float*)d_in[3];
    const float* bias    = (const float*)d_in[4];
    float*       out     = (float*)d_out;

    // ws: Z f16[(N+1)*D] | Wf f16[16384] | hist int[HB*NR] | total int[NR] |
    //     rangeStart int[NR] | part uint[E]   (~18 MB)
    _Float16*     Z      = (_Float16*)d_ws;
    _Float16*     Wf     = Z + (size_t)(N + 1) * D;
    int*          hist   = (int*)(Wf + 16384);
    int*          total  = hist + HB * NR;
    int*          rangeS = total + NR;
    unsigned int* part   = (unsigned int*)(rangeS + NR);

    setup<<<9, 256, 0, stream>>>(W, Wf, Z);
    midk <<<HB + (NT + 3) / 4, 256, 0, stream>>>(feature, edst, Wf, hist, Z);
    scank<<<NR, 64, 0, stream>>>(hist, total);
    partk<<<HB, 256, 0, stream>>>(esrc, edst, hist, total, rangeS, part);
    csrgather<<<NR, 256, 0, stream>>>(part, rangeS, total, Z, bias, out);
}